// Round 4
// baseline (7899.863 us; speedup 1.0000x reference)
//
#include <hip/hip_runtime.h>

#define NN 8192
#define DD 32
#define SLOTS 104
// stagger-padded LDS index: +4 floats of pad per 16 (keeps 16B alignment)
#define SIDX(c) ((c) + 4 * ((c) >> 4))

constexpr float kEps   = 0.1f;
constexpr float kStab  = 1e-8f;
constexpr float kMass  = 1.0f / 8192.0f;     // mu = nu = 1/n
constexpr float kInvSc = 1.0f / 256.0f;      // K stored as fp8 of 256*K
constexpr float kLnSc  = 5.545177444479562f; // ln(256)
constexpr float kTol   = 5e-7f;              // rel-Δu convergence tolerance

typedef float v2f __attribute__((ext_vector_type(2)));

__device__ inline void cvt8x4(unsigned int w, float* out) {
    v2f lo = __builtin_amdgcn_cvt_pk_f32_fp8(w, false);
    v2f hi = __builtin_amdgcn_cvt_pk_f32_fp8(w, true);
    out[0] = lo.x; out[1] = lo.y; out[2] = hi.x; out[3] = hi.y;
}
__device__ inline void cvt16(uint4 kk, float* f) {
    cvt8x4(kk.x, f); cvt8x4(kk.y, f + 4); cvt8x4(kk.z, f + 8); cvt8x4(kk.w, f + 12);
}
__device__ inline unsigned int pack8x4(float a, float b, float c, float d) {
    int v = 0;
    v = __builtin_amdgcn_cvt_pk_fp8_f32(a, b, v, false);
    v = __builtin_amdgcn_cvt_pk_fp8_f32(c, d, v, true);
    return (unsigned int)v;
}

// skip test: slot bits != 0 (written) and < tol bits.  (0 = "no data yet")
__device__ inline bool sk_skip(const unsigned int* dslot, int z, int it) {
    if (it < 2) return false;
    unsigned int b = dslot[z * SLOTS + it - 2];
    return (b - 1u) < (__float_as_uint(kTol) - 1u);
}

// ---------------------------------------------------------------- init u = 1
__global__ void sk_init_u(float* __restrict__ u) {
    u[blockIdx.x * 256 + threadIdx.x] = 1.0f;
}

// -------------------------------- build K8 = fp8(256*exp(-cost/eps)), z = transport
__global__ __launch_bounds__(256) void sk_build_k(const float* __restrict__ src,
                                                  const float* __restrict__ tgt,
                                                  unsigned char* __restrict__ K8,
                                                  int nb) {
    const int z = blockIdx.z;
    const float* X = src; const float* Y = tgt;
    if (nb == 3) { if (z == 1) Y = src; else if (z == 2) { X = tgt; } }
    unsigned char* K = K8 + (size_t)z * NN * NN;

    __shared__ float xs[DD * 64];
    __shared__ float ys[DD * 64];
    __shared__ float sx[64], sy[64];
    const int t  = threadIdx.x;
    const int r0 = blockIdx.y * 64, c0 = blockIdx.x * 64;

    for (int idx = t; idx < DD * 64; idx += 256) {
        int d = idx >> 6, row = idx & 63;
        xs[idx] = X[(size_t)(r0 + row) * DD + d];
        ys[idx] = Y[(size_t)(c0 + row) * DD + d];
    }
    __syncthreads();
    if (t < 64) {
        float s = 0.f;
        for (int d = 0; d < DD; d++) { float v = xs[d * 64 + t]; s = fmaf(v, v, s); }
        sx[t] = s;
    } else if (t < 128) {
        int q = t - 64; float s = 0.f;
        for (int d = 0; d < DD; d++) { float v = ys[d * 64 + q]; s = fmaf(v, v, s); }
        sy[q] = s;
    }
    __syncthreads();

    const int tr = t >> 4, tc = t & 15;
    float acc[4][4] = {};
    for (int d = 0; d < DD; d++) {
        const float4 xa = *reinterpret_cast<const float4*>(&xs[d * 64 + 4 * tr]);
        const float4 yb = *reinterpret_cast<const float4*>(&ys[d * 64 + 4 * tc]);
        const float xav[4] = {xa.x, xa.y, xa.z, xa.w};
        const float ybv[4] = {yb.x, yb.y, yb.z, yb.w};
#pragma unroll
        for (int a = 0; a < 4; a++)
#pragma unroll
            for (int b = 0; b < 4; b++) acc[a][b] = fmaf(xav[a], ybv[b], acc[a][b]);
    }
#pragma unroll
    for (int a = 0; a < 4; a++) {
        const int r = r0 + 4 * tr + a;
        const float sxa = sx[4 * tr + a];
        float e[4];
#pragma unroll
        for (int b = 0; b < 4; b++) {
            float cost = sxa + sy[4 * tc + b] - 2.0f * acc[a][b];
            cost = fmaxf(cost, 0.0f);
            e[b] = __expf(fmaf(-10.0f, cost, kLnSc));   // 256 * exp(-cost/eps)
        }
        *reinterpret_cast<unsigned int*>(&K[(size_t)r * NN + c0 + 4 * tc]) =
            pack8x4(e[0], e[1], e[2], e[3]);
    }
}

// -------------------------------- column sums: rc[z] += K[z]^T u[z]
__global__ __launch_bounds__(256) void sk_colsum(const unsigned char* __restrict__ K8,
                                                 const float* __restrict__ u,
                                                 float* __restrict__ rc_out,
                                                 const unsigned int* __restrict__ dslot,
                                                 int it) {
    const int z = blockIdx.z;
    if (sk_skip(dslot, z, it)) return;

    __shared__ float us[128];
    __shared__ float red[4 * 1280];   // 4 waves x staggered 1024
    const int t = threadIdx.x, lane = t & 63, w = t >> 6;
    const int c0 = blockIdx.x * 1024, r0 = blockIdx.y * 128;
    const unsigned char* K = K8 + (size_t)z * NN * NN;
    if (t < 128) us[t] = u[z * NN + r0 + t];
    __syncthreads();

    float acc[16] = {};
    const unsigned char* p = K + (size_t)(r0 + 32 * w) * NN + c0 + 16 * lane;
    for (int i = 0; i < 32; i += 4) {
        uint4 k0 = *reinterpret_cast<const uint4*>(p);
        uint4 k1 = *reinterpret_cast<const uint4*>(p + (size_t)NN);
        uint4 k2 = *reinterpret_cast<const uint4*>(p + (size_t)2 * NN);
        uint4 k3 = *reinterpret_cast<const uint4*>(p + (size_t)3 * NN);
        p += (size_t)4 * NN;
        const float u0 = us[32 * w + i + 0], u1 = us[32 * w + i + 1];
        const float u2 = us[32 * w + i + 2], u3 = us[32 * w + i + 3];
        float f[16];
        cvt16(k0, f);
#pragma unroll
        for (int j = 0; j < 16; j++) acc[j] = fmaf(f[j], u0, acc[j]);
        cvt16(k1, f);
#pragma unroll
        for (int j = 0; j < 16; j++) acc[j] = fmaf(f[j], u1, acc[j]);
        cvt16(k2, f);
#pragma unroll
        for (int j = 0; j < 16; j++) acc[j] = fmaf(f[j], u2, acc[j]);
        cvt16(k3, f);
#pragma unroll
        for (int j = 0; j < 16; j++) acc[j] = fmaf(f[j], u3, acc[j]);
    }
    float* rw = &red[w * 1280 + 20 * lane];   // SIDX(16*lane) = 20*lane
#pragma unroll
    for (int g = 0; g < 4; g++) {
        float4 v = {acc[4 * g + 0], acc[4 * g + 1], acc[4 * g + 2], acc[4 * g + 3]};
        *reinterpret_cast<float4*>(rw + 4 * g) = v;
    }
    __syncthreads();
    for (int c = t; c < 1024; c += 256) {
        const int sc = SIDX(c);
        const float s = red[sc] + red[1280 + sc] + red[2560 + sc] + red[3840 + sc];
        atomicAdd(&rc_out[z * NN + c0 + c], s);
    }
}

// -------------------------------- row sums: u[z] = m/(K[z] v + stab)
// Also: writes v slice to vbuf, measures max rel-Δu into dslot[z][it].
__global__ __launch_bounds__(256) void sk_rowsum(const unsigned char* __restrict__ K8,
                                                 const float* __restrict__ rc_in,
                                                 float* __restrict__ u_out,
                                                 float* __restrict__ rc_zero,
                                                 float* __restrict__ vbuf,
                                                 unsigned int* __restrict__ dslot,
                                                 int it) {
    const int z = blockIdx.z;
    if (sk_skip(dslot, z, it)) {
        if (threadIdx.x == 0) dslot[z * SLOTS + it] = 1u;   // propagate skip
        return;
    }

    __shared__ float vs[10240];   // staggered 8192
    __shared__ float dred[4];
    const int t = threadIdx.x;
    const unsigned char* K = K8 + (size_t)z * NN * NN;
    const float* rc = rc_in + z * NN;

#pragma unroll
    for (int q = 0; q < 8; q++) {
        const int j = 4 * t + 1024 * q;
        float4 r = *reinterpret_cast<const float4*>(rc + j);
        float4 g;
        g.x = kMass * __builtin_amdgcn_rcpf(fmaf(r.x, kInvSc, kStab));
        g.y = kMass * __builtin_amdgcn_rcpf(fmaf(r.y, kInvSc, kStab));
        g.z = kMass * __builtin_amdgcn_rcpf(fmaf(r.z, kInvSc, kStab));
        g.w = kMass * __builtin_amdgcn_rcpf(fmaf(r.w, kInvSc, kStab));
        *reinterpret_cast<float4*>(&vs[SIDX(j)]) = g;
        if ((j >> 5) == blockIdx.x)          // this block's 32-wide v slice
            *reinterpret_cast<float4*>(&vbuf[z * NN + j]) = g;
    }
    {   // zero the other rc buffer: grid covers nb*NN floats, 32 per block
        const int flat = blockIdx.z * gridDim.x + blockIdx.x;
        if (t < 32) rc_zero[flat * 32 + t] = 0.0f;
    }
    __syncthreads();

    const int lane = t & 63, w = t >> 6;
    const int rbase = blockIdx.x * 32 + 8 * w;
    float acc[8] = {};
    const unsigned char* rp = K + (size_t)rbase * NN + 16 * lane;
    for (int s = 0; s < 8; s++) {
        const float* vp = &vs[20 * lane + 1280 * s];   // SIDX(16*lane + 1024*s)
        const float4 va = *reinterpret_cast<const float4*>(vp);
        const float4 vb = *reinterpret_cast<const float4*>(vp + 4);
        const float4 vc = *reinterpret_cast<const float4*>(vp + 8);
        const float4 vd = *reinterpret_cast<const float4*>(vp + 12);
        const unsigned char* ps = rp + 1024 * s;
#pragma unroll
        for (int r = 0; r < 8; r++) {
            uint4 kk = *reinterpret_cast<const uint4*>(ps + (size_t)r * NN);
            float f[16];
            cvt16(kk, f);
            float a = acc[r];
            a = fmaf(f[0],  va.x, a); a = fmaf(f[1],  va.y, a);
            a = fmaf(f[2],  va.z, a); a = fmaf(f[3],  va.w, a);
            a = fmaf(f[4],  vb.x, a); a = fmaf(f[5],  vb.y, a);
            a = fmaf(f[6],  vb.z, a); a = fmaf(f[7],  vb.w, a);
            a = fmaf(f[8],  vc.x, a); a = fmaf(f[9],  vc.y, a);
            a = fmaf(f[10], vc.z, a); a = fmaf(f[11], vc.w, a);
            a = fmaf(f[12], vd.x, a); a = fmaf(f[13], vd.y, a);
            a = fmaf(f[14], vd.z, a); a = fmaf(f[15], vd.w, a);
            acc[r] = a;
        }
    }
    float lm = 0.f;
#pragma unroll
    for (int r = 0; r < 8; r++) {
        float p = acc[r];
        for (int off = 32; off > 0; off >>= 1) p += __shfl_down(p, off);
        if (lane == 0) {
            const int gi = z * NN + rbase + r;
            const float uo = u_out[gi];
            const float un = kMass / (p * kInvSc + kStab);
            u_out[gi] = un;
            lm = fmaxf(lm, fabsf(un - uo) * __builtin_amdgcn_rcpf(uo));
        }
    }
    if (lane == 0) dred[w] = lm;
    __syncthreads();
    if (t == 0) {
        float m4 = fmaxf(fmaxf(dred[0], dred[1]), fmaxf(dred[2], dred[3]));
        atomicMax(&dslot[z * SLOTS + it], __float_as_uint(m4));
    }
}

// -------------------------------- w[z] = sum u_i K_ij v_j cost_ij, cost = -eps*ln(K)
__global__ __launch_bounds__(256) void sk_wsum(const unsigned char* __restrict__ K8,
                                               const float* __restrict__ vbuf,
                                               const float* __restrict__ u,
                                               double* __restrict__ acc_out) {
    __shared__ float vs[10240];
    __shared__ double wred[4];
    const int t = threadIdx.x;
    const int z = blockIdx.z;
    const unsigned char* K = K8 + (size_t)z * NN * NN;
    const float* vb = vbuf + z * NN;
#pragma unroll
    for (int q = 0; q < 8; q++) {
        const int j = 4 * t + 1024 * q;
        float4 g = *reinterpret_cast<const float4*>(vb + j);
        *reinterpret_cast<float4*>(&vs[SIDX(j)]) = g;
    }
    __syncthreads();

    const int lane = t & 63, w = t >> 6;
    const int rbase = blockIdx.x * 32 + 8 * w;
    float pr[8] = {};
    const unsigned char* rp = K + (size_t)rbase * NN + 16 * lane;
    for (int s = 0; s < 8; s++) {
        const float* vp = &vs[20 * lane + 1280 * s];
        float vv[16];
#pragma unroll
        for (int g = 0; g < 4; g++) {
            float4 v4 = *reinterpret_cast<const float4*>(vp + 4 * g);
            vv[4 * g] = v4.x; vv[4 * g + 1] = v4.y; vv[4 * g + 2] = v4.z; vv[4 * g + 3] = v4.w;
        }
        const unsigned char* ps = rp + 1024 * s;
#pragma unroll
        for (int r = 0; r < 8; r++) {
            uint4 kk = *reinterpret_cast<const uint4*>(ps + (size_t)r * NN);
            float f[16];
            cvt16(kk, f);
            float a = pr[r];
#pragma unroll
            for (int j = 0; j < 16; j++)
                a = fmaf(f[j] * vv[j], __logf(fmaxf(f[j], 1e-30f) * kInvSc), a);
            pr[r] = a;
        }
    }
    double lacc = 0.0;
#pragma unroll
    for (int r = 0; r < 8; r++)
        lacc += (double)(u[z * NN + rbase + r] * pr[r]);
    lacc *= (double)kInvSc;
    for (int off = 32; off > 0; off >>= 1) lacc += __shfl_down(lacc, off);
    if (lane == 0) wred[w] = lacc;
    __syncthreads();
    if (t == 0) {
        double total = -(double)kEps * (wred[0] + wred[1] + wred[2] + wred[3]);
        atomicAdd(&acc_out[z], total);
    }
}

// ------------------------------------------------- combine
__global__ void sk_combine(const double* __restrict__ acc, float* __restrict__ out) {
    if (threadIdx.x == 0)
        out[0] = (float)((acc[0] - 0.5 * acc[1] - 0.5 * acc[2]) / 8192.0);
}

extern "C" void kernel_launch(void* const* d_in, const int* in_sizes, int n_in,
                              void* d_out, int out_size, void* d_ws, size_t ws_size,
                              hipStream_t stream) {
    const float* src = (const float*)d_in[0];
    const float* tgt = (const float*)d_in[1];
    float* out = (float*)d_out;
    char* ws = (char*)d_ws;

    const size_t need3 = 3ull * NN * NN + 20ull * NN * sizeof(float) + 4096;
    const bool batched = ws_size >= need3;
    const int B = batched ? 3 : 1;

    const size_t koff = (size_t)B * NN * NN;
    unsigned char* K8 = (unsigned char*)ws;
    float*  u    = (float*)(ws + koff);
    float*  raw0 = u + (size_t)B * NN;
    float*  raw1 = raw0 + (size_t)B * NN;
    float*  vbuf = raw1 + (size_t)B * NN;
    double* wacc = (double*)(vbuf + (size_t)B * NN);
    unsigned int* dslot = (unsigned int*)(wacc + 3);
    float* raws[2] = {raw0, raw1};

    // zero wacc (3 doubles) + dslot (3*SLOTS uints) in one shot
    hipMemsetAsync(wacc, 0, 3 * sizeof(double) + 3 * SLOTS * sizeof(unsigned int),
                   stream);

    if (batched) {
        hipMemsetAsync(raw0, 0, 2ull * 3 * NN * sizeof(float), stream);
        sk_init_u<<<3 * NN / 256, 256, 0, stream>>>(u);
        sk_build_k<<<dim3(128, 128, 3), 256, 0, stream>>>(src, tgt, K8, 3);
        for (int it = 0; it < 100; it++) {
            sk_colsum<<<dim3(8, 64, 3), 256, 0, stream>>>(K8, u, raws[it & 1],
                                                          dslot, it);
            sk_rowsum<<<dim3(256, 1, 3), 256, 0, stream>>>(K8, raws[it & 1], u,
                                                           raws[(it + 1) & 1],
                                                           vbuf, dslot, it);
        }
        sk_wsum<<<dim3(256, 1, 3), 256, 0, stream>>>(K8, vbuf, u, wacc);
    } else {
        const float* pts[3][2] = {{src, tgt}, {src, src}, {tgt, tgt}};
        for (int tf = 0; tf < 3; tf++) {
            hipMemsetAsync(raw0, 0, 2ull * NN * sizeof(float), stream);
            sk_init_u<<<NN / 256, 256, 0, stream>>>(u);
            sk_build_k<<<dim3(128, 128, 1), 256, 0, stream>>>(pts[tf][0], pts[tf][1],
                                                              K8, 1);
            unsigned int* ds = dslot + tf * SLOTS;
            for (int it = 0; it < 100; it++) {
                sk_colsum<<<dim3(8, 64, 1), 256, 0, stream>>>(K8, u, raws[it & 1],
                                                              ds, it);
                sk_rowsum<<<dim3(256, 1, 1), 256, 0, stream>>>(K8, raws[it & 1], u,
                                                               raws[(it + 1) & 1],
                                                               vbuf, ds, it);
            }
            sk_wsum<<<dim3(256, 1, 1), 256, 0, stream>>>(K8, vbuf, u, &wacc[tf]);
        }
    }
    sk_combine<<<1, 64, 0, stream>>>(wacc, out);
}